// Round 10
// baseline (363.458 us; speedup 1.0000x reference)
//
#include <hip/hip_runtime.h>

#define DFEAT 64
#define SCAN_B 1024

__device__ __forceinline__ float bf2f(unsigned short u) {
    return __uint_as_float(((unsigned)u) << 16);
}
__device__ __forceinline__ unsigned short f2bf(float f) {
    unsigned u = __float_as_uint(f);
    return (unsigned short)((u + 0x7FFFu + ((u >> 16) & 1u)) >> 16);  // RNE
}

__global__ void k_zero_deg(int* __restrict__ deg, int N) {
    int i = blockIdx.x * blockDim.x + threadIdx.x;
    if (i < N) deg[i] = 0;
}

// histogram + per-edge rank, 4 edges/thread (standalone: fusing anything here hurts)
__global__ __launch_bounds__(256, 8) void k_histv(
        const int* __restrict__ dst, int* __restrict__ deg,
        int* __restrict__ rank, int E) {
    int t = blockIdx.x * blockDim.x + threadIdx.x;
    int E4 = E >> 2;
    if (t < E4) {
        int4 d = reinterpret_cast<const int4*>(dst)[t];
        int4 r;
        r.x = atomicAdd(&deg[d.x], 1);
        r.y = atomicAdd(&deg[d.y], 1);
        r.z = atomicAdd(&deg[d.z], 1);
        r.w = atomicAdd(&deg[d.w], 1);
        reinterpret_cast<int4*>(rank)[t] = r;
    }
    if (t == 0) {
        for (int e = E4 * 4; e < E; ++e) rank[e] = atomicAdd(&deg[dst[e]], 1);
    }
}

// ---------- exclusive scan of deg -> rowstart (+ dinv fused) ----------
__global__ void k_scan_block(const int* __restrict__ deg, int* __restrict__ excl,
                             int* __restrict__ blockSums, float* __restrict__ dinv, int N) {
    __shared__ int sm[SCAN_B];
    int gid = blockIdx.x * SCAN_B + threadIdx.x;
    int v = (gid < N) ? deg[gid] : 0;
    if (gid < N) dinv[gid] = rsqrtf(1.0f + (float)v);  // +1 = self-loop
    sm[threadIdx.x] = v;
    __syncthreads();
    for (int off = 1; off < SCAN_B; off <<= 1) {
        int t = (threadIdx.x >= off) ? sm[threadIdx.x - off] : 0;
        __syncthreads();
        sm[threadIdx.x] += t;
        __syncthreads();
    }
    if (gid < N) excl[gid] = sm[threadIdx.x] - v;
    if (threadIdx.x == SCAN_B - 1) blockSums[blockIdx.x] = sm[threadIdx.x];
}

__global__ void k_scan_sums(int* __restrict__ blockSums, int nb) {
    __shared__ int sm[SCAN_B];
    int v = (threadIdx.x < nb) ? blockSums[threadIdx.x] : 0;
    sm[threadIdx.x] = v;
    __syncthreads();
    for (int off = 1; off < SCAN_B; off <<= 1) {
        int t = (threadIdx.x >= off) ? sm[threadIdx.x - off] : 0;
        __syncthreads();
        sm[threadIdx.x] += t;
        __syncthreads();
    }
    if (threadIdx.x < nb) blockSums[threadIdx.x] = sm[threadIdx.x] - v;  // exclusive
}

__global__ void k_add_offsets(const int* __restrict__ excl, const int* __restrict__ blockSums,
                              int* __restrict__ rowstart, int N, int E) {
    int gid = blockIdx.x * SCAN_B + threadIdx.x;
    if (gid < N) rowstart[gid] = excl[gid] + blockSums[blockIdx.x];
    else if (gid == N) rowstart[N] = E;
}

// ---------- fused: CSR fill (x4 vec) + layer-1 GEMM (scaled) ----------
__global__ __launch_bounds__(256, 4) void k_fill_gemm1(
        const int* __restrict__ src, const int* __restrict__ dst,
        const int* __restrict__ rank, const int* __restrict__ rowstart,
        int* __restrict__ eid, int E, int fillBlocks,
        const float* __restrict__ h, const float* __restrict__ W,
        const float* __restrict__ dinv, unsigned short* __restrict__ gbf, int N) {
    __shared__ float Wl[DFEAT * DFEAT];
    int tid = threadIdx.x;

    if ((int)blockIdx.x < fillBlocks) {
        int t = blockIdx.x * blockDim.x + tid;
        int E4 = E >> 2;
        if (t < E4) {
            int4 s = reinterpret_cast<const int4*>(src)[t];
            int4 d = reinterpret_cast<const int4*>(dst)[t];
            int4 r = reinterpret_cast<const int4*>(rank)[t];
            eid[rowstart[d.x] + r.x] = s.x;
            eid[rowstart[d.y] + r.y] = s.y;
            eid[rowstart[d.z] + r.z] = s.z;
            eid[rowstart[d.w] + r.w] = s.w;
        }
        if (t == 0) {
            for (int e = E4 * 4; e < E; ++e) eid[rowstart[dst[e]] + rank[e]] = src[e];
        }
        return;
    }

    // ---- gemm path ----
    #pragma unroll
    for (int i = 0; i < 16; ++i) Wl[tid + i * 256] = W[tid + i * 256];
    __syncthreads();

    int r = (blockIdx.x - fillBlocks) * 16 + (tid >> 4);
    if (r >= N) return;
    int c0 = (tid & 15) * 4;

    const float4* h4 = reinterpret_cast<const float4*>(h + (size_t)r * DFEAT);
    float4 hr[16];
    #pragma unroll
    for (int j = 0; j < 16; ++j) hr[j] = h4[j];

    float a0 = 0.f, a1 = 0.f, a2 = 0.f, a3 = 0.f;
    #pragma unroll
    for (int j = 0; j < 16; ++j) {
        float4 hv = hr[j];
        float4 w0 = *reinterpret_cast<const float4*>(&Wl[(4 * j + 0) * DFEAT + c0]);
        float4 w1 = *reinterpret_cast<const float4*>(&Wl[(4 * j + 1) * DFEAT + c0]);
        float4 w2 = *reinterpret_cast<const float4*>(&Wl[(4 * j + 2) * DFEAT + c0]);
        float4 w3 = *reinterpret_cast<const float4*>(&Wl[(4 * j + 3) * DFEAT + c0]);
        a0 = fmaf(hv.x, w0.x, a0); a1 = fmaf(hv.x, w0.y, a1);
        a2 = fmaf(hv.x, w0.z, a2); a3 = fmaf(hv.x, w0.w, a3);
        a0 = fmaf(hv.y, w1.x, a0); a1 = fmaf(hv.y, w1.y, a1);
        a2 = fmaf(hv.y, w1.z, a2); a3 = fmaf(hv.y, w1.w, a3);
        a0 = fmaf(hv.z, w2.x, a0); a1 = fmaf(hv.z, w2.y, a1);
        a2 = fmaf(hv.z, w2.z, a2); a3 = fmaf(hv.z, w2.w, a3);
        a0 = fmaf(hv.w, w3.x, a0); a1 = fmaf(hv.w, w3.y, a1);
        a2 = fmaf(hv.w, w3.z, a2); a3 = fmaf(hv.w, w3.w, a3);
    }
    float di = dinv[r];
    ushort4 o;
    o.x = f2bf(a0 * di); o.y = f2bf(a1 * di);
    o.z = f2bf(a2 * di); o.w = f2bf(a3 * di);
    *reinterpret_cast<ushort4*>(&gbf[(size_t)r * DFEAT + c0]) = o;
}

// ---------- standalone GEMM (layers 2,3) ----------
__global__ __launch_bounds__(256, 4) void k_gemm_scale(
        const float* __restrict__ h, const float* __restrict__ W,
        const float* __restrict__ dinv, unsigned short* __restrict__ gbf, int N) {
    __shared__ float Wl[DFEAT * DFEAT];
    int tid = threadIdx.x;
    #pragma unroll
    for (int i = 0; i < 16; ++i) Wl[tid + i * 256] = W[tid + i * 256];
    __syncthreads();

    int r = blockIdx.x * 16 + (tid >> 4);
    if (r >= N) return;
    int c0 = (tid & 15) * 4;

    const float4* h4 = reinterpret_cast<const float4*>(h + (size_t)r * DFEAT);
    float4 hr[16];
    #pragma unroll
    for (int j = 0; j < 16; ++j) hr[j] = h4[j];

    float a0 = 0.f, a1 = 0.f, a2 = 0.f, a3 = 0.f;
    #pragma unroll
    for (int j = 0; j < 16; ++j) {
        float4 hv = hr[j];
        float4 w0 = *reinterpret_cast<const float4*>(&Wl[(4 * j + 0) * DFEAT + c0]);
        float4 w1 = *reinterpret_cast<const float4*>(&Wl[(4 * j + 1) * DFEAT + c0]);
        float4 w2 = *reinterpret_cast<const float4*>(&Wl[(4 * j + 2) * DFEAT + c0]);
        float4 w3 = *reinterpret_cast<const float4*>(&Wl[(4 * j + 3) * DFEAT + c0]);
        a0 = fmaf(hv.x, w0.x, a0); a1 = fmaf(hv.x, w0.y, a1);
        a2 = fmaf(hv.x, w0.z, a2); a3 = fmaf(hv.x, w0.w, a3);
        a0 = fmaf(hv.y, w1.x, a0); a1 = fmaf(hv.y, w1.y, a1);
        a2 = fmaf(hv.y, w1.z, a2); a3 = fmaf(hv.y, w1.w, a3);
        a0 = fmaf(hv.z, w2.x, a0); a1 = fmaf(hv.z, w2.y, a1);
        a2 = fmaf(hv.z, w2.z, a2); a3 = fmaf(hv.z, w2.w, a3);
        a0 = fmaf(hv.w, w3.x, a0); a1 = fmaf(hv.w, w3.y, a1);
        a2 = fmaf(hv.w, w3.z, a2); a3 = fmaf(hv.w, w3.w, a3);
    }
    float di = dinv[r];
    ushort4 o;
    o.x = f2bf(a0 * di); o.y = f2bf(a1 * di);
    o.z = f2bf(a2 * di); o.w = f2bf(a3 * di);
    *reinterpret_cast<ushort4*>(&gbf[(size_t)r * DFEAT + c0]) = o;
}

// ---------- pull-aggregate: XCD-affine feature-half, 4 neighbor-slots/wave ----------
// blockIdx&1 selects 32-feature half (64B line of the 128B row). With bid%8->XCD
// round-robin, each XCD's L2 only caches one half of g (6.4MB vs 12.8MB).
// Wave = 1 node: slot = lane>>4 (4 neighbors per vmem instr), fu = lane&15 (uint).
__global__ __launch_bounds__(256, 8) void k_agg_half(
        const unsigned short* __restrict__ g,
        const int* __restrict__ rowstart, const int* __restrict__ eid,
        const float* __restrict__ dinv, const float* __restrict__ b,
        float* __restrict__ hout, int N, int npw) {
    int tid = threadIdx.x;
    int half = blockIdx.x & 1;
    int wvh = ((int)blockIdx.x >> 1) * 4 + (tid >> 6);   // wave id within half
    int lane = tid & 63;
    int slot = lane >> 4;
    int fu = lane & 15;
    int hb = half * 16;  // uint offset of the half within a 32-uint row

    int n0 = wvh * npw;
    int n1 = n0 + npw; if (n1 > N) n1 = N;
    if (n0 >= N) return;

    const unsigned* g32 = reinterpret_cast<const unsigned*>(g);
    float2 bias = *reinterpret_cast<const float2*>(&b[half * 32 + 2 * fu]);

    for (int node = n0; node < n1; ++node) {
        int s0 = __builtin_amdgcn_readfirstlane(rowstart[node]);
        int s1 = __builtin_amdgcn_readfirstlane(rowstart[node + 1]);

        float ax = 0.f, ay = 0.f, cx = 0.f, cy = 0.f;
        for (int base = s0; base < s1; base += 8) {
            int i1 = base + slot, i2 = base + 4 + slot;
            bool v1 = i1 < s1, v2 = i2 < s1;
            int e1 = eid[v1 ? i1 : s0];
            int e2 = eid[v2 ? i2 : s0];
            unsigned u1 = g32[(size_t)e1 * 32 + hb + fu];
            unsigned u2 = g32[(size_t)e2 * 32 + hb + fu];
            if (v1) { ax += bf2f((unsigned short)u1); ay += bf2f((unsigned short)(u1 >> 16)); }
            if (v2) { cx += bf2f((unsigned short)u2); cy += bf2f((unsigned short)(u2 >> 16)); }
        }
        ax += cx; ay += cy;
        // reduce across the 4 slots
        ax += __shfl_xor(ax, 16, 64);
        ax += __shfl_xor(ax, 32, 64);
        ay += __shfl_xor(ay, 16, 64);
        ay += __shfl_xor(ay, 32, 64);

        if (slot == 0) {
            unsigned us = g32[(size_t)node * 32 + hb + fu];  // self-loop
            ax += bf2f((unsigned short)us);
            ay += bf2f((unsigned short)(us >> 16));
            float di = dinv[node];
            float2 o;
            o.x = fmaxf(fmaf(di, ax, bias.x), 0.f);
            o.y = fmaxf(fmaf(di, ay, bias.y), 0.f);
            *reinterpret_cast<float2*>(&hout[(size_t)node * DFEAT + half * 32 + 2 * fu]) = o;
        }
    }
}

extern "C" void kernel_launch(void* const* d_in, const int* in_sizes, int n_in,
                              void* d_out, int out_size, void* d_ws, size_t ws_size,
                              hipStream_t stream) {
    const float* x  = (const float*)d_in[0];
    const float* W1 = (const float*)d_in[1];
    const float* b1 = (const float*)d_in[2];
    const float* W2 = (const float*)d_in[3];
    const float* b2 = (const float*)d_in[4];
    const float* W3 = (const float*)d_in[5];
    const float* b3 = (const float*)d_in[6];
    const int* eidx = (const int*)d_in[7];  // int64 under default JAX -> int32

    const int N = in_sizes[0] / DFEAT;   // 100000
    const int E = in_sizes[7] / 2;       // 1000000
    const int* esrc = eidx;
    const int* edst = eidx + E;

    auto align64 = [](size_t v) { return (v + 63) & ~(size_t)63; };
    char* wp = (char*)d_ws;
    int*   deg       = (int*)wp;              wp += align64((size_t)N * 4);
    float* dinv      = (float*)wp;            wp += align64((size_t)N * 4);
    int*   excl      = (int*)wp;              wp += align64((size_t)N * 4);
    int*   blockSums = (int*)wp;              wp += align64((size_t)SCAN_B * 4);
    int*   rowstart  = (int*)wp;              wp += align64((size_t)(N + 1) * 4);
    int*   rank      = (int*)wp;              wp += align64((size_t)E * 4);
    int*   eid       = (int*)wp;              wp += align64((size_t)E * 4);
    unsigned short* gbfA = (unsigned short*)wp; wp += align64((size_t)N * DFEAT * 2);
    unsigned short* gbfB = (unsigned short*)wp; wp += align64((size_t)N * DFEAT * 2);
    float* hbuf      = (float*)wp;            wp += align64((size_t)N * DFEAT * 4);
    float* out = (float*)d_out;

    const int B = 256;
    const int nScanBlocks = (N + SCAN_B) / SCAN_B + 1;

    const int histBlocks = ((E >> 2) + B - 1) / B;      // 977
    const int fillBlocks = histBlocks;
    const int gemm_grid  = (N + 15) / 16;               // 6250

    const int agg_blocks = 4096;                        // 2048 per feature-half
    const int wavesPerHalf = (agg_blocks / 2) * 4;      // 8192
    const int npw = (N + wavesPerHalf - 1) / wavesPerHalf;  // 13

    // ---- CSR build (once, reused 3x) ----
    k_zero_deg<<<(N + B - 1) / B, B, 0, stream>>>(deg, N);
    k_histv<<<histBlocks, B, 0, stream>>>(edst, deg, rank, E);
    k_scan_block<<<(N + SCAN_B - 1) / SCAN_B, SCAN_B, 0, stream>>>(deg, excl, blockSums, dinv, N);
    k_scan_sums<<<1, SCAN_B, 0, stream>>>(blockSums, (N + SCAN_B - 1) / SCAN_B);
    k_add_offsets<<<nScanBlocks, SCAN_B, 0, stream>>>(excl, blockSums, rowstart, N, E);
    k_fill_gemm1<<<fillBlocks + gemm_grid, B, 0, stream>>>(
        esrc, edst, rank, rowstart, eid, E, fillBlocks, x, W1, dinv, gbfA, N);

    // layer 1
    k_agg_half<<<agg_blocks, B, 0, stream>>>(gbfA, rowstart, eid, dinv, b1, hbuf, N, npw);
    // layer 2
    k_gemm_scale<<<gemm_grid, B, 0, stream>>>(hbuf, W2, dinv, gbfB, N);
    k_agg_half<<<agg_blocks, B, 0, stream>>>(gbfB, rowstart, eid, dinv, b2, hbuf, N, npw);
    // layer 3
    k_gemm_scale<<<gemm_grid, B, 0, stream>>>(hbuf, W3, dinv, gbfA, N);
    k_agg_half<<<agg_blocks, B, 0, stream>>>(gbfA, rowstart, eid, dinv, b3, out, N, npw);
}

// Round 11
// 248.590 us; speedup vs baseline: 1.4621x; 1.4621x over previous
//
#include <hip/hip_runtime.h>

#define DFEAT 64
#define SCAN_B 1024

__device__ __forceinline__ float bf2f(unsigned short u) {
    return __uint_as_float(((unsigned)u) << 16);
}
__device__ __forceinline__ unsigned short f2bf(float f) {
    unsigned u = __float_as_uint(f);
    return (unsigned short)((u + 0x7FFFu + ((u >> 16) & 1u)) >> 16);  // RNE
}

__global__ void k_zero_deg(int* __restrict__ deg, int N) {
    int i = blockIdx.x * blockDim.x + threadIdx.x;
    if (i < N) deg[i] = 0;
}

// histogram + per-edge rank, 4 edges/thread. ~43us = device atomic-with-return
// throughput floor (measured invariant across 1x/4x thread mappings, R6/R7).
__global__ __launch_bounds__(256, 8) void k_histv(
        const int* __restrict__ dst, int* __restrict__ deg,
        int* __restrict__ rank, int E) {
    int t = blockIdx.x * blockDim.x + threadIdx.x;
    int E4 = E >> 2;
    if (t < E4) {
        int4 d = reinterpret_cast<const int4*>(dst)[t];
        int4 r;
        r.x = atomicAdd(&deg[d.x], 1);
        r.y = atomicAdd(&deg[d.y], 1);
        r.z = atomicAdd(&deg[d.z], 1);
        r.w = atomicAdd(&deg[d.w], 1);
        reinterpret_cast<int4*>(rank)[t] = r;
    }
    if (t == 0) {
        for (int e = E4 * 4; e < E; ++e) rank[e] = atomicAdd(&deg[dst[e]], 1);
    }
}

// ---------- exclusive scan of deg -> rowstart (+ dinv fused) ----------
__global__ void k_scan_block(const int* __restrict__ deg, int* __restrict__ excl,
                             int* __restrict__ blockSums, float* __restrict__ dinv, int N) {
    __shared__ int sm[SCAN_B];
    int gid = blockIdx.x * SCAN_B + threadIdx.x;
    int v = (gid < N) ? deg[gid] : 0;
    if (gid < N) dinv[gid] = rsqrtf(1.0f + (float)v);  // +1 = self-loop
    sm[threadIdx.x] = v;
    __syncthreads();
    for (int off = 1; off < SCAN_B; off <<= 1) {
        int t = (threadIdx.x >= off) ? sm[threadIdx.x - off] : 0;
        __syncthreads();
        sm[threadIdx.x] += t;
        __syncthreads();
    }
    if (gid < N) excl[gid] = sm[threadIdx.x] - v;
    if (threadIdx.x == SCAN_B - 1) blockSums[blockIdx.x] = sm[threadIdx.x];
}

__global__ void k_scan_sums(int* __restrict__ blockSums, int nb) {
    __shared__ int sm[SCAN_B];
    int v = (threadIdx.x < nb) ? blockSums[threadIdx.x] : 0;
    sm[threadIdx.x] = v;
    __syncthreads();
    for (int off = 1; off < SCAN_B; off <<= 1) {
        int t = (threadIdx.x >= off) ? sm[threadIdx.x - off] : 0;
        __syncthreads();
        sm[threadIdx.x] += t;
        __syncthreads();
    }
    if (threadIdx.x < nb) blockSums[threadIdx.x] = sm[threadIdx.x] - v;  // exclusive
}

__global__ void k_add_offsets(const int* __restrict__ excl, const int* __restrict__ blockSums,
                              int* __restrict__ rowstart, int N, int E) {
    int gid = blockIdx.x * SCAN_B + threadIdx.x;
    if (gid < N) rowstart[gid] = excl[gid] + blockSums[blockIdx.x];
    else if (gid == N) rowstart[N] = E;
}

// ---------- fused: CSR fill (x4 vec) + layer-1 GEMM (scaled, f32 input x) ----------
__global__ __launch_bounds__(256, 4) void k_fill_gemm1(
        const int* __restrict__ src, const int* __restrict__ dst,
        const int* __restrict__ rank, const int* __restrict__ rowstart,
        int* __restrict__ eid, int E, int fillBlocks,
        const float* __restrict__ h, const float* __restrict__ W,
        const float* __restrict__ dinv, unsigned short* __restrict__ gbf, int N) {
    __shared__ float Wl[DFEAT * DFEAT];
    int tid = threadIdx.x;

    if ((int)blockIdx.x < fillBlocks) {
        int t = blockIdx.x * blockDim.x + tid;
        int E4 = E >> 2;
        if (t < E4) {
            int4 s = reinterpret_cast<const int4*>(src)[t];
            int4 d = reinterpret_cast<const int4*>(dst)[t];
            int4 r = reinterpret_cast<const int4*>(rank)[t];
            eid[rowstart[d.x] + r.x] = s.x;
            eid[rowstart[d.y] + r.y] = s.y;
            eid[rowstart[d.z] + r.z] = s.z;
            eid[rowstart[d.w] + r.w] = s.w;
        }
        if (t == 0) {
            for (int e = E4 * 4; e < E; ++e) eid[rowstart[dst[e]] + rank[e]] = src[e];
        }
        return;
    }

    #pragma unroll
    for (int i = 0; i < 16; ++i) Wl[tid + i * 256] = W[tid + i * 256];
    __syncthreads();

    int r = (blockIdx.x - fillBlocks) * 16 + (tid >> 4);
    if (r >= N) return;
    int c0 = (tid & 15) * 4;

    const float4* h4 = reinterpret_cast<const float4*>(h + (size_t)r * DFEAT);
    float4 hr[16];
    #pragma unroll
    for (int j = 0; j < 16; ++j) hr[j] = h4[j];

    float a0 = 0.f, a1 = 0.f, a2 = 0.f, a3 = 0.f;
    #pragma unroll
    for (int j = 0; j < 16; ++j) {
        float4 hv = hr[j];
        float4 w0 = *reinterpret_cast<const float4*>(&Wl[(4 * j + 0) * DFEAT + c0]);
        float4 w1 = *reinterpret_cast<const float4*>(&Wl[(4 * j + 1) * DFEAT + c0]);
        float4 w2 = *reinterpret_cast<const float4*>(&Wl[(4 * j + 2) * DFEAT + c0]);
        float4 w3 = *reinterpret_cast<const float4*>(&Wl[(4 * j + 3) * DFEAT + c0]);
        a0 = fmaf(hv.x, w0.x, a0); a1 = fmaf(hv.x, w0.y, a1);
        a2 = fmaf(hv.x, w0.z, a2); a3 = fmaf(hv.x, w0.w, a3);
        a0 = fmaf(hv.y, w1.x, a0); a1 = fmaf(hv.y, w1.y, a1);
        a2 = fmaf(hv.y, w1.z, a2); a3 = fmaf(hv.y, w1.w, a3);
        a0 = fmaf(hv.z, w2.x, a0); a1 = fmaf(hv.z, w2.y, a1);
        a2 = fmaf(hv.z, w2.z, a2); a3 = fmaf(hv.z, w2.w, a3);
        a0 = fmaf(hv.w, w3.x, a0); a1 = fmaf(hv.w, w3.y, a1);
        a2 = fmaf(hv.w, w3.z, a2); a3 = fmaf(hv.w, w3.w, a3);
    }
    float di = dinv[r];
    ushort4 o;
    o.x = f2bf(a0 * di); o.y = f2bf(a1 * di);
    o.z = f2bf(a2 * di); o.w = f2bf(a3 * di);
    *reinterpret_cast<ushort4*>(&gbf[(size_t)r * DFEAT + c0]) = o;
}

// ---------- GEMM (layers 2,3): bf16 h input -> gbf = bf16((h @ W) * dinv) ----------
__global__ __launch_bounds__(256, 4) void k_gemm_scale_bf(
        const unsigned short* __restrict__ h, const float* __restrict__ W,
        const float* __restrict__ dinv, unsigned short* __restrict__ gbf, int N) {
    __shared__ float Wl[DFEAT * DFEAT];
    int tid = threadIdx.x;
    #pragma unroll
    for (int i = 0; i < 16; ++i) Wl[tid + i * 256] = W[tid + i * 256];
    __syncthreads();

    int r = blockIdx.x * 16 + (tid >> 4);
    if (r >= N) return;
    int c0 = (tid & 15) * 4;

    const ushort4* h4 = reinterpret_cast<const ushort4*>(h + (size_t)r * DFEAT);
    ushort4 hr[16];
    #pragma unroll
    for (int j = 0; j < 16; ++j) hr[j] = h4[j];  // 8B loads, wave-uniform rows

    float a0 = 0.f, a1 = 0.f, a2 = 0.f, a3 = 0.f;
    #pragma unroll
    for (int j = 0; j < 16; ++j) {
        float hx = bf2f(hr[j].x), hy = bf2f(hr[j].y);
        float hz = bf2f(hr[j].z), hw = bf2f(hr[j].w);
        float4 w0 = *reinterpret_cast<const float4*>(&Wl[(4 * j + 0) * DFEAT + c0]);
        float4 w1 = *reinterpret_cast<const float4*>(&Wl[(4 * j + 1) * DFEAT + c0]);
        float4 w2 = *reinterpret_cast<const float4*>(&Wl[(4 * j + 2) * DFEAT + c0]);
        float4 w3 = *reinterpret_cast<const float4*>(&Wl[(4 * j + 3) * DFEAT + c0]);
        a0 = fmaf(hx, w0.x, a0); a1 = fmaf(hx, w0.y, a1);
        a2 = fmaf(hx, w0.z, a2); a3 = fmaf(hx, w0.w, a3);
        a0 = fmaf(hy, w1.x, a0); a1 = fmaf(hy, w1.y, a1);
        a2 = fmaf(hy, w1.z, a2); a3 = fmaf(hy, w1.w, a3);
        a0 = fmaf(hz, w2.x, a0); a1 = fmaf(hz, w2.y, a1);
        a2 = fmaf(hz, w2.z, a2); a3 = fmaf(hz, w2.w, a3);
        a0 = fmaf(hw, w3.x, a0); a1 = fmaf(hw, w3.y, a1);
        a2 = fmaf(hw, w3.z, a2); a3 = fmaf(hw, w3.w, a3);
    }
    float di = dinv[r];
    ushort4 o;
    o.x = f2bf(a0 * di); o.y = f2bf(a1 * di);
    o.z = f2bf(a2 * di); o.w = f2bf(a3 * di);
    *reinterpret_cast<ushort4*>(&gbf[(size_t)r * DFEAT + c0]) = o;
}

// ---------- pull-aggregate (layers 1,2): bf16 h output, oversubscribed waves ----------
__global__ __launch_bounds__(256, 8) void k_agg_bf(
        const unsigned short* __restrict__ g,
        const int* __restrict__ rowstart, const int* __restrict__ eid,
        const float* __restrict__ dinv, const float* __restrict__ b,
        unsigned short* __restrict__ hout, int N, int npw) {
    int wv = (blockIdx.x * blockDim.x + threadIdx.x) >> 6;
    int lane = threadIdx.x & 63;
    int n0 = wv * npw;
    int n1 = n0 + npw; if (n1 > N) n1 = N;
    if (n0 >= N) return;
    float bias = b[lane];

    for (int node = n0; node < n1; ++node) {
        int s0 = __builtin_amdgcn_readfirstlane(rowstart[node]);
        int s1 = __builtin_amdgcn_readfirstlane(rowstart[node + 1]);

        float accA = bf2f(g[(size_t)node * DFEAT + lane]);  // self-loop term
        float accB = 0.f;
        int i = s0;
        for (; i + 8 <= s1; i += 8) {
            int e0 = eid[i + 0], e1 = eid[i + 1], e2 = eid[i + 2], e3 = eid[i + 3];
            int e4 = eid[i + 4], e5 = eid[i + 5], e6 = eid[i + 6], e7 = eid[i + 7];
            float v0 = bf2f(g[(size_t)e0 * DFEAT + lane]);
            float v1 = bf2f(g[(size_t)e1 * DFEAT + lane]);
            float v2 = bf2f(g[(size_t)e2 * DFEAT + lane]);
            float v3 = bf2f(g[(size_t)e3 * DFEAT + lane]);
            float v4 = bf2f(g[(size_t)e4 * DFEAT + lane]);
            float v5 = bf2f(g[(size_t)e5 * DFEAT + lane]);
            float v6 = bf2f(g[(size_t)e6 * DFEAT + lane]);
            float v7 = bf2f(g[(size_t)e7 * DFEAT + lane]);
            accA += (v0 + v1) + (v2 + v3);
            accB += (v4 + v5) + (v6 + v7);
        }
        for (; i + 2 <= s1; i += 2) {
            int e0 = eid[i], e1 = eid[i + 1];
            accA += bf2f(g[(size_t)e0 * DFEAT + lane]);
            accB += bf2f(g[(size_t)e1 * DFEAT + lane]);
        }
        if (i < s1) accA += bf2f(g[(size_t)eid[i] * DFEAT + lane]);

        hout[(size_t)node * DFEAT + lane] =
            f2bf(fmaxf(fmaf(dinv[node], accA + accB, bias), 0.f));
    }
}

// ---------- final aggregate (layer 3): f32 output ----------
__global__ __launch_bounds__(256, 8) void k_agg_f32(
        const unsigned short* __restrict__ g,
        const int* __restrict__ rowstart, const int* __restrict__ eid,
        const float* __restrict__ dinv, const float* __restrict__ b,
        float* __restrict__ hout, int N, int npw) {
    int wv = (blockIdx.x * blockDim.x + threadIdx.x) >> 6;
    int lane = threadIdx.x & 63;
    int n0 = wv * npw;
    int n1 = n0 + npw; if (n1 > N) n1 = N;
    if (n0 >= N) return;
    float bias = b[lane];

    for (int node = n0; node < n1; ++node) {
        int s0 = __builtin_amdgcn_readfirstlane(rowstart[node]);
        int s1 = __builtin_amdgcn_readfirstlane(rowstart[node + 1]);

        float accA = bf2f(g[(size_t)node * DFEAT + lane]);
        float accB = 0.f;
        int i = s0;
        for (; i + 8 <= s1; i += 8) {
            int e0 = eid[i + 0], e1 = eid[i + 1], e2 = eid[i + 2], e3 = eid[i + 3];
            int e4 = eid[i + 4], e5 = eid[i + 5], e6 = eid[i + 6], e7 = eid[i + 7];
            float v0 = bf2f(g[(size_t)e0 * DFEAT + lane]);
            float v1 = bf2f(g[(size_t)e1 * DFEAT + lane]);
            float v2 = bf2f(g[(size_t)e2 * DFEAT + lane]);
            float v3 = bf2f(g[(size_t)e3 * DFEAT + lane]);
            float v4 = bf2f(g[(size_t)e4 * DFEAT + lane]);
            float v5 = bf2f(g[(size_t)e5 * DFEAT + lane]);
            float v6 = bf2f(g[(size_t)e6 * DFEAT + lane]);
            float v7 = bf2f(g[(size_t)e7 * DFEAT + lane]);
            accA += (v0 + v1) + (v2 + v3);
            accB += (v4 + v5) + (v6 + v7);
        }
        for (; i + 2 <= s1; i += 2) {
            int e0 = eid[i], e1 = eid[i + 1];
            accA += bf2f(g[(size_t)e0 * DFEAT + lane]);
            accB += bf2f(g[(size_t)e1 * DFEAT + lane]);
        }
        if (i < s1) accA += bf2f(g[(size_t)eid[i] * DFEAT + lane]);

        hout[(size_t)node * DFEAT + lane] = fmaxf(fmaf(dinv[node], accA + accB, bias), 0.f);
    }
}

extern "C" void kernel_launch(void* const* d_in, const int* in_sizes, int n_in,
                              void* d_out, int out_size, void* d_ws, size_t ws_size,
                              hipStream_t stream) {
    const float* x  = (const float*)d_in[0];
    const float* W1 = (const float*)d_in[1];
    const float* b1 = (const float*)d_in[2];
    const float* W2 = (const float*)d_in[3];
    const float* b2 = (const float*)d_in[4];
    const float* W3 = (const float*)d_in[5];
    const float* b3 = (const float*)d_in[6];
    const int* eidx = (const int*)d_in[7];  // int64 under default JAX -> int32

    const int N = in_sizes[0] / DFEAT;   // 100000
    const int E = in_sizes[7] / 2;       // 1000000
    const int* esrc = eidx;
    const int* edst = eidx + E;

    auto align64 = [](size_t v) { return (v + 63) & ~(size_t)63; };
    char* wp = (char*)d_ws;
    int*   deg       = (int*)wp;              wp += align64((size_t)N * 4);
    float* dinv      = (float*)wp;            wp += align64((size_t)N * 4);
    int*   excl      = (int*)wp;              wp += align64((size_t)N * 4);
    int*   blockSums = (int*)wp;              wp += align64((size_t)SCAN_B * 4);
    int*   rowstart  = (int*)wp;              wp += align64((size_t)(N + 1) * 4);
    int*   rank      = (int*)wp;              wp += align64((size_t)E * 4);
    int*   eid       = (int*)wp;              wp += align64((size_t)E * 4);
    unsigned short* gbfA = (unsigned short*)wp; wp += align64((size_t)N * DFEAT * 2);
    unsigned short* gbfB = (unsigned short*)wp; wp += align64((size_t)N * DFEAT * 2);
    unsigned short* hbuf = (unsigned short*)wp; wp += align64((size_t)N * DFEAT * 2);
    float* out = (float*)d_out;

    const int B = 256;
    const int nScanBlocks = (N + SCAN_B) / SCAN_B + 1;

    const int histBlocks = ((E >> 2) + B - 1) / B;      // 977
    const int fillBlocks = histBlocks;
    const int gemm_grid  = (N + 15) / 16;               // 6250

    const int agg_blocks = 4096;                        // 16384 waves (2x oversubscribe)
    const int agg_waves  = agg_blocks * 4;
    const int npw = (N + agg_waves - 1) / agg_waves;    // 7 nodes/wave

    // ---- CSR build (once, reused 3x) ----
    k_zero_deg<<<(N + B - 1) / B, B, 0, stream>>>(deg, N);
    k_histv<<<histBlocks, B, 0, stream>>>(edst, deg, rank, E);
    k_scan_block<<<(N + SCAN_B - 1) / SCAN_B, SCAN_B, 0, stream>>>(deg, excl, blockSums, dinv, N);
    k_scan_sums<<<1, SCAN_B, 0, stream>>>(blockSums, (N + SCAN_B - 1) / SCAN_B);
    k_add_offsets<<<nScanBlocks, SCAN_B, 0, stream>>>(excl, blockSums, rowstart, N, E);
    k_fill_gemm1<<<fillBlocks + gemm_grid, B, 0, stream>>>(
        esrc, edst, rank, rowstart, eid, E, fillBlocks, x, W1, dinv, gbfA, N);

    // layer 1
    k_agg_bf<<<agg_blocks, B, 0, stream>>>(gbfA, rowstart, eid, dinv, b1, hbuf, N, npw);
    // layer 2
    k_gemm_scale_bf<<<gemm_grid, B, 0, stream>>>(hbuf, W2, dinv, gbfB, N);
    k_agg_bf<<<agg_blocks, B, 0, stream>>>(gbfB, rowstart, eid, dinv, b2, hbuf, N, npw);
    // layer 3
    k_gemm_scale_bf<<<gemm_grid, B, 0, stream>>>(hbuf, W3, dinv, gbfA, N);
    k_agg_f32<<<agg_blocks, B, 0, stream>>>(gbfA, rowstart, eid, dinv, b3, out, N, npw);
}